// Round 13
// baseline (199.578 us; speedup 1.0000x reference)
//
#include <hip/hip_runtime.h>
#include <cstdint>
#include <cstddef>

// ---------------------------------------------------------------------------
// AttnBlock, 5 dispatches, every GEMM grid = exactly one resident round:
//   prep:   GN(1-pass)->hT[16384][512]; wqk/wpb bf16; bqk; rowsum=0;
//           W2 = wp.wv (fp32 FMA, 128 blocks); bpv = wp.bv
//   qk:     qkT[16384][1024] = hT.wqk^T + bqk        (512 BM256 = 1 round)
//   scores: E[b][i][j] = exp(rsK*q.k); rowsum atomic (512 BM256 = 1 round)
//   vP:     vP[b][co][j] = sum_c W2[co][c] hT[(b,j)][c] + bpv[co] (512 BM128)
//   PV':    out[(b,c)][i] = x + bp[c] + (sum_j vP.E)/rowsum       (512 BM128)
// Engine: BM x 128 tiles, 4 waves, BK=64, chunk-swizzled LDS, XCD remap.
// launch_bounds: BM256 (256,2) / BM128 (256,3) -- (256,3) on BM256 SPILLS
// (R10: VGPR 84, 344MB scratch writes). Do not raise.
// Grid-size rule (R12 lesson): BM256 dispatch > 512 blocks adds a full
// straggler round (~20us). Keep grids <= capacity.
// ---------------------------------------------------------------------------

typedef __bf16 bf16x8 __attribute__((ext_vector_type(8)));
typedef float f32x4 __attribute__((ext_vector_type(4)));

typedef __attribute__((address_space(1))) const void gl_void;
typedef __attribute__((address_space(3))) void lds_void;

#define GLD16(g, l)                                                     \
  __builtin_amdgcn_global_load_lds((gl_void*)(uintptr_t)(g),            \
                                   (lds_void*)(uintptr_t)(l), 16, 0, 0)

__device__ __forceinline__ unsigned short f2bf(float f) {
  unsigned int u = __builtin_bit_cast(unsigned int, f);
  u += 0x7fffu + ((u >> 16) & 1u);  // round-to-nearest-even
  return (unsigned short)(u >> 16);
}
__device__ __forceinline__ float bf2f(unsigned int h) {
  return __builtin_bit_cast(float, h << 16);
}

// ---- prep: GN (0-511) + weights (512-1535) + W2/bpv (1536-1663) -----------
__global__ __launch_bounds__(256) void prep_kernel(
    const float* __restrict__ x, const float* __restrict__ gsc,
    const float* __restrict__ gbi, unsigned short* __restrict__ hT,
    const float* __restrict__ wq, const float* __restrict__ wk,
    const float* __restrict__ wv, const float* __restrict__ wp,
    const float* __restrict__ bq, const float* __restrict__ bk,
    const float* __restrict__ bv, unsigned short* __restrict__ oqk,
    unsigned short* __restrict__ opb, unsigned short* __restrict__ W2o,
    float* __restrict__ bqk, float* __restrict__ bpv,
    float* __restrict__ rowsum) {
  const int t = threadIdx.x;
  if (blockIdx.x >= 1536) {  // ---- W2 = wp.wv (fp32), bpv = wp.bv ----
    const int o0 = (blockIdx.x - 1536) * 4;  // 4 output rows per block
    float a0[4] = {}, a1[4] = {}, bs[4] = {};
    for (int c = 0; c < 512; ++c) {
      const float v0 = wv[(size_t)c * 512 + t];        // j = t  (coalesced)
      const float v1 = wv[(size_t)c * 512 + 256 + t];  // j = t+256
      const float bc = bv[c];                          // uniform -> s_load
#pragma unroll
      for (int r = 0; r < 4; ++r) {
        const float w = wp[(size_t)(o0 + r) * 512 + c];  // uniform -> s_load
        a0[r] += w * v0;
        a1[r] += w * v1;
        bs[r] += w * bc;
      }
    }
#pragma unroll
    for (int r = 0; r < 4; ++r) {
      W2o[(size_t)(o0 + r) * 512 + t] = f2bf(a0[r]);
      W2o[(size_t)(o0 + r) * 512 + 256 + t] = f2bf(a1[r]);
    }
    if (t == 0) {
#pragma unroll
      for (int r = 0; r < 4; ++r) bpv[o0 + r] = bs[r];
    }
    return;
  }
  if (blockIdx.x >= 512) {  // ---- weights fp32 -> bf16, bias, rowsum=0 ----
    const int idx = (blockIdx.x - 512) * 256 + t;  // 0..262143
    oqk[idx] = f2bf(wq[idx]);
    oqk[262144 + idx] = f2bf(wk[idx]);
    opb[idx] = f2bf(wp[idx]);
    if (idx < 1024) bqk[idx] = idx < 512 ? bq[idx] : bk[idx - 512];
    if (idx < 16384) rowsum[idx] = 0.f;
    return;
  }
  // ---- GroupNorm -> hT[b][i][c] bf16 (transposed), single pass ----
  __shared__ float red[2][4];
  const int b = blockIdx.x >> 5;
  const int g = blockIdx.x & 31;
  const int wid = t >> 6, lane = t & 63;
  const float* xp = x + ((size_t)(b * 512 + g * 16)) * 1024;

  float4 r4[16];  // 16 chans x 4 consecutive hw-elements (i = 4t..4t+3)
  float s = 0.f, s2 = 0.f;
#pragma unroll
  for (int c = 0; c < 16; ++c) {
    r4[c] = ((const float4*)(xp + (size_t)c * 1024))[t];
    s += (r4[c].x + r4[c].y) + (r4[c].z + r4[c].w);
    s2 += (r4[c].x * r4[c].x + r4[c].y * r4[c].y) +
          (r4[c].z * r4[c].z + r4[c].w * r4[c].w);
  }
#pragma unroll
  for (int off = 32; off > 0; off >>= 1) {
    s += __shfl_down(s, off);
    s2 += __shfl_down(s2, off);
  }
  if (lane == 0) { red[0][wid] = s; red[1][wid] = s2; }
  __syncthreads();
  const float S = red[0][0] + red[0][1] + red[0][2] + red[0][3];
  const float S2 = red[1][0] + red[1][1] + red[1][2] + red[1][3];
  const float mean = S * (1.f / 16384.f);
  const float var = S2 * (1.f / 16384.f) - mean * mean;
  const float rstd = rsqrtf(var + 1e-6f);

  float sc[16], bi[16];
#pragma unroll
  for (int c = 0; c < 16; ++c) {
    sc[c] = gsc[g * 16 + c] * rstd;
    bi[c] = gbi[g * 16 + c] - mean * sc[c];
  }
  unsigned short* hp = hT + (size_t)b * 1024 * 512 + g * 16;
#pragma unroll
  for (int ii = 0; ii < 4; ++ii) {  // ii indexes float4 component
    const int i = 4 * t + ii;
    unsigned int pk[8];
#pragma unroll
    for (int c = 0; c < 8; ++c) {
      float e0, e1;
      if (ii == 0) { e0 = r4[2 * c].x; e1 = r4[2 * c + 1].x; }
      else if (ii == 1) { e0 = r4[2 * c].y; e1 = r4[2 * c + 1].y; }
      else if (ii == 2) { e0 = r4[2 * c].z; e1 = r4[2 * c + 1].z; }
      else { e0 = r4[2 * c].w; e1 = r4[2 * c + 1].w; }
      float v0 = e0 * sc[2 * c] + bi[2 * c];
      float v1 = e1 * sc[2 * c + 1] + bi[2 * c + 1];
      pk[c] = (unsigned int)f2bf(v0) | ((unsigned int)f2bf(v1) << 16);
    }
    uint4* dst = (uint4*)(hp + (size_t)i * 512);
    dst[0] = make_uint4(pk[0], pk[1], pk[2], pk[3]);
    dst[1] = make_uint4(pk[4], pk[5], pk[6], pk[7]);
  }
}

// ------------------------- NT GEMM engine ----------------------------------
// D[m][n] = scale * sum_k A[m][k]*Bt[n][k].
// epi 0: plain  (+bias bmode{1:[gm],2:[gn]}, +resid, csplit offset)
// epi 2: exp + atomic rowsum (scores; bf16 out, row-major)
// epi 4: PV': v/rowsum[(m0>>9)*1024+gn] + bias[gm&511] + resid; fp32 row-major
struct GArgs {
  const unsigned short *A, *B;
  void* Out;
  const float *bias, *resid;
  float* rowsum;
  long long sBb, sOb;
  int lda, ldb, ldo, btshift, obf, csplit, K, bmode, nx, nwg, epi;
  float scale;
};

template <int BM>
__global__ __launch_bounds__(256, (BM == 256 ? 2 : 3)) void gemm_nt(
    GArgs g0, GArgs g1, int split) {
  constexpr int MF = BM / 32;      // m-frags per wave (8 / 4)
  constexpr int WMS = BM / 2;      // wave m-span (128 / 64)
  constexpr int ASLABS = BM / 32;  // A staging slabs (8 / 4)
  constexpr int BOFF = BM * 128;   // byte offset of B region in LDS
  __shared__ char lds[BM * 128 + 16384];

  const bool r1 = (int)blockIdx.x >= split;
  const GArgs g = r1 ? g1 : g0;
  const int lid = blockIdx.x - (r1 ? split : 0);

  // XCD-chunked remap within role (nwg % 8 == 0 for all our grids)
  const int cpx = g.nwg >> 3;
  const int rid = (lid & 7) * cpx + (lid >> 3);
  const int bx = rid % g.nx, by = rid / g.nx;
  const int m0 = by * BM, n0 = bx * 128;

  const int t = threadIdx.x;
  const int wid = t >> 6, lane = t & 63;
  const int srow = t >> 3;                        // 32-row slab row
  const int schunk = ((t & 7) ^ (srow & 7)) * 8;  // pre-swizzled src chunk
  const unsigned short* gA = g.A + (size_t)(m0 + srow) * g.lda + schunk;
  const unsigned short* gB =
      g.B + (g.btshift ? (size_t)(m0 >> g.btshift) * g.sBb : 0) +
      (size_t)(n0 + srow) * g.ldb + schunk;
  const int stgO = wid << 10;  // wave-uniform 1KB sub-slab

  f32x4 acc[MF][4] = {};
  const int wm = wid >> 1, wn = wid & 1;
  const int fr = lane & 15;
  const int slot0 = (((lane >> 4) ^ (fr & 7)) << 4);
  const int aoff = (wm * WMS + fr) * 128 + slot0;
  const int boff = BOFF + (wn * 64 + fr) * 128 + slot0;

  const int nt = g.K >> 6;
  for (int tt = 0; tt < nt; ++tt) {
    const size_t ko = (size_t)tt * 64;
#pragma unroll
    for (int c = 0; c < ASLABS; ++c)
      GLD16(gA + ko + (size_t)(c * 32) * g.lda, lds + c * 4096 + stgO);
#pragma unroll
    for (int c = 0; c < 4; ++c)
      GLD16(gB + ko + (size_t)(c * 32) * g.ldb, lds + BOFF + c * 4096 + stgO);
    __syncthreads();  // drains vmcnt -> tile visible to all waves
#pragma unroll
    for (int kk = 0; kk < 2; ++kk) {
      const int kx = kk ? 64 : 0;  // second k-half: chunk slot ^= 4
      bf16x8 av[MF], bv[4];
#pragma unroll
      for (int mf = 0; mf < MF; ++mf)
        av[mf] = *(const bf16x8*)(lds + ((aoff + mf * 2048) ^ kx));
#pragma unroll
      for (int nf = 0; nf < 4; ++nf)
        bv[nf] = *(const bf16x8*)(lds + ((boff + nf * 2048) ^ kx));
      __builtin_amdgcn_s_setprio(1);
#pragma unroll
      for (int mf = 0; mf < MF; ++mf)
#pragma unroll
        for (int nf = 0; nf < 4; ++nf)
          acc[mf][nf] = __builtin_amdgcn_mfma_f32_16x16x32_bf16(
              av[mf], bv[nf], acc[mf][nf], 0, 0, 0);
      __builtin_amdgcn_s_setprio(0);
    }
    __syncthreads();  // protect LDS before next stage
  }

  const int em = m0 + wm * WMS + (lane >> 4) * 4;
  const int en = n0 + wn * 64 + fr;

  float rdiv[4];
  if (g.epi == 4) {
    const int rbase = (m0 >> 9) << 10;  // batch = m0>>9, E-row base
#pragma unroll
    for (int nf = 0; nf < 4; ++nf)
      rdiv[nf] = 1.f / g.rowsum[rbase + en + nf * 16];
  }

#pragma unroll
  for (int mf = 0; mf < MF; ++mf) {
#pragma unroll
    for (int r = 0; r < 4; ++r) {
      const int gm = em + mf * 16 + r;
      if (g.epi == 2) {  // scores: exp, atomic row sum of ROUNDED values
        float rsum = 0.f;
#pragma unroll
        for (int nf = 0; nf < 4; ++nf) {
          const int gn = en + nf * 16;
          unsigned short h = f2bf(__expf(acc[mf][nf][r] * g.scale));
          rsum += bf2f(h);
          ((unsigned short*)g.Out)[(size_t)gm * g.ldo + gn] = h;
        }
        rsum += __shfl_xor(rsum, 1);
        rsum += __shfl_xor(rsum, 2);
        rsum += __shfl_xor(rsum, 4);
        rsum += __shfl_xor(rsum, 8);
        if ((lane & 15) == 0) atomicAdd(&g.rowsum[gm], rsum);
        continue;
      }
      if (g.epi == 4) {  // PV': normalize + bias + resid, fp32 row-major
        const float bb = g.bias[gm & 511];
#pragma unroll
        for (int nf = 0; nf < 4; ++nf) {
          const int gn = en + nf * 16;
          const size_t off = (size_t)gm * g.ldo + gn;
          ((float*)g.Out)[off] = acc[mf][nf][r] * rdiv[nf] + bb + g.resid[off];
        }
        continue;
      }
#pragma unroll
      for (int nf = 0; nf < 4; ++nf) {
        const int gn = en + nf * 16;
        float v = acc[mf][nf][r] * g.scale;
        if (g.bmode == 1) v += g.bias[gm];
        else if (g.bmode == 2) v += g.bias[gn];
        size_t off;
        if (g.csplit)
          off = (size_t)(gn >> 10) * g.sOb + (size_t)gm * g.ldo + (gn & 1023);
        else
          off = (size_t)gm * g.ldo + gn;
        if (g.resid) v += g.resid[off];
        if (g.obf) ((unsigned short*)g.Out)[off] = f2bf(v);
        else ((float*)g.Out)[off] = v;
      }
    }
  }
}

// ---------------------------------------------------------------------------
extern "C" void kernel_launch(void* const* d_in, const int* in_sizes, int n_in,
                              void* d_out, int out_size, void* d_ws,
                              size_t ws_size, hipStream_t stream) {
  const float* x   = (const float*)d_in[0];
  const float* gsc = (const float*)d_in[1];
  const float* gbi = (const float*)d_in[2];
  const float* wq  = (const float*)d_in[3];
  const float* bq  = (const float*)d_in[4];
  const float* wk  = (const float*)d_in[5];
  const float* bk  = (const float*)d_in[6];
  const float* wv  = (const float*)d_in[7];
  const float* bv  = (const float*)d_in[8];
  const float* wp  = (const float*)d_in[9];
  const float* bp  = (const float*)d_in[10];
  float* out = (float*)d_out;

  char* ws = (char*)d_ws;
  const size_t MB = 1024ull * 1024ull;
  unsigned short* hT  = (unsigned short*)(ws);             // 16MB [16384][512]
  unsigned short* qkT = (unsigned short*)(ws + 16 * MB);   // 32MB [16384][1024]
  unsigned short* E   = (unsigned short*)(ws + 48 * MB);   // 32MB [16384][1024]
  unsigned short* vP  = (unsigned short*)(ws + 80 * MB);   // 16MB [16][512][1024]
  unsigned short* wqk = (unsigned short*)(ws + 96 * MB);   // 1MB  [1024][512]
  unsigned short* wpb = (unsigned short*)(ws + 97 * MB);   // 0.5MB
  unsigned short* W2  = (unsigned short*)(ws + 98 * MB);   // 0.5MB [512][512]
  float*          bqk = (float*)(ws + 99 * MB);            // 4KB
  float*          bpv = (float*)(ws + 99 * MB + 8 * 1024); // 2KB
  float*          rowsum = (float*)(ws + 99 * MB + 16 * 1024);  // 64KB

  prep_kernel<<<1664, 256, 0, stream>>>(x, gsc, gbi, hT, wq, wk, wv, wp,
                                        bq, bk, bv, wqk, wpb, W2,
                                        bqk, bpv, rowsum);

  const float rsK = 0.04419417382415922f;  // 512^-0.5

  // qk: qkT[m][n] = sum_c hT[m][c] wqk[n][c] + bqk[n]  (512 tiles, 1 round)
  GArgs qk{hT, wqk, qkT, bqk, nullptr, nullptr, 0, 0,
           512, 512, 1024, 0, 1, 0, 512, 2, 8, 512, 0, 1.f};
  // scores: E[m][j] = exp(rsK * q_m . k_{b,j}); rowsum atomic. b = m>>10.
  GArgs sc{qkT, qkT + 512, E, nullptr, nullptr, rowsum, 1048576, 0,
           1024, 1024, 1024, 10, 1, 0, 512, 0, 8, 512, 2, rsK};
  // vP[b][co][j] = sum_c W2[co][c] hT[(b,j)][c] + bpv[co]  (csplit writes)
  GArgs vp{W2, hT, vP, bpv, nullptr, nullptr, 0, 524288,
           512, 512, 1024, 0, 1, 1, 512, 1, 128, 512, 0, 1.f};
  // PV': out[(b,c)][i] = x + bp[c] + (sum_j vP[(b,c)][j] E[b][i][j])/rowsum
  GArgs pv{vP, E, out, bp, x, rowsum, 1048576, 0,
           1024, 1024, 1024, 9, 0, 0, 1024, 0, 8, 512, 4, 1.f};

  gemm_nt<256><<<512, 256, 0, stream>>>(qk, qk, 512);
  gemm_nt<256><<<512, 256, 0, stream>>>(sc, sc, 512);
  gemm_nt<128><<<512, 256, 0, stream>>>(vp, vp, 512);
  gemm_nt<128><<<512, 256, 0, stream>>>(pv, pv, 512);
}

// Round 14
// 182.771 us; speedup vs baseline: 1.0920x; 1.0920x over previous
//
#include <hip/hip_runtime.h>
#include <cstdint>
#include <cstddef>

// ---------------------------------------------------------------------------
// AttnBlock, 5 dispatches, every GEMM grid = exactly one resident round:
//   prep:   GN(1-pass)->hT[16384][512]; wqk bf16; bqk; rowsum=0;
//           W2 = wp.wv (fp32, LDS-staged wp -> throughput-bound); bpv = wp.bv
//   qk:     qkT[16384][1024] = hT.wqk^T + bqk        (512 BM256 = 1 round)
//   scores: E[b][i][j] = exp(rsK*q.k); rowsum atomic (512 BM256 = 1 round)
//   vP:     vP[b][co][j] = sum_c W2[co][c] hT[(b,j)][c] + bpv[co] (512 BM128)
//   PV':    out[(b,c)][i] = x + bp[c] + (sum_j vP.E)/rowsum       (512 BM128)
// Engine: BM x 128 tiles, 4 waves, BK=64, chunk-swizzled LDS, XCD remap.
// launch_bounds: BM256 (256,2) / BM128 (256,3) -- (256,3) on BM256 SPILLS
// (R10: VGPR 84, 344MB scratch writes). Do not raise.
// Grid rule (R12): BM256 grids > 512 blocks add a straggler round. Keep <=512.
// W2 rule (R13): wave-uniform wp[o][c] reads in a K-loop serialize as s_loads
// (~+60us). Stage wp/bv in LDS first; only wv streams from global.
// ---------------------------------------------------------------------------

typedef __bf16 bf16x8 __attribute__((ext_vector_type(8)));
typedef float f32x4 __attribute__((ext_vector_type(4)));

typedef __attribute__((address_space(1))) const void gl_void;
typedef __attribute__((address_space(3))) void lds_void;

#define GLD16(g, l)                                                     \
  __builtin_amdgcn_global_load_lds((gl_void*)(uintptr_t)(g),            \
                                   (lds_void*)(uintptr_t)(l), 16, 0, 0)

__device__ __forceinline__ unsigned short f2bf(float f) {
  unsigned int u = __builtin_bit_cast(unsigned int, f);
  u += 0x7fffu + ((u >> 16) & 1u);  // round-to-nearest-even
  return (unsigned short)(u >> 16);
}
__device__ __forceinline__ float bf2f(unsigned int h) {
  return __builtin_bit_cast(float, h << 16);
}

// ---- prep: GN (0-511) + qk weights (512-1535) + W2/bpv (1536-1663) --------
__global__ __launch_bounds__(256) void prep_kernel(
    const float* __restrict__ x, const float* __restrict__ gsc,
    const float* __restrict__ gbi, unsigned short* __restrict__ hT,
    const float* __restrict__ wq, const float* __restrict__ wk,
    const float* __restrict__ wv, const float* __restrict__ wp,
    const float* __restrict__ bq, const float* __restrict__ bk,
    const float* __restrict__ bv, unsigned short* __restrict__ oqk,
    unsigned short* __restrict__ W2o, float* __restrict__ bqk,
    float* __restrict__ bpv, float* __restrict__ rowsum) {
  const int t = threadIdx.x;
  if (blockIdx.x >= 1536) {  // ---- W2 = wp.wv (fp32), bpv = wp.bv ----
    __shared__ float swp[4][512];  // wp rows o0..o0+3 (LDS, not s_loads!)
    __shared__ float sbv[512];
    __shared__ float redp[4][4];
    const int o0 = (blockIdx.x - 1536) * 4;  // 4 output rows per block
#pragma unroll
    for (int r = 0; r < 4; ++r) {
      swp[r][t] = wp[(size_t)(o0 + r) * 512 + t];
      swp[r][256 + t] = wp[(size_t)(o0 + r) * 512 + 256 + t];
    }
    sbv[t] = bv[t];
    sbv[256 + t] = bv[256 + t];
    __syncthreads();
    float a0[4] = {}, a1[4] = {};
    for (int c = 0; c < 512; ++c) {
      const float v0 = wv[(size_t)c * 512 + t];        // coalesced, L2
      const float v1 = wv[(size_t)c * 512 + 256 + t];  // coalesced, L2
#pragma unroll
      for (int r = 0; r < 4; ++r) {  // swp[r][c]: LDS broadcast (cheap)
        a0[r] = fmaf(swp[r][c], v0, a0[r]);
        a1[r] = fmaf(swp[r][c], v1, a1[r]);
      }
    }
#pragma unroll
    for (int r = 0; r < 4; ++r) {
      W2o[(size_t)(o0 + r) * 512 + t] = f2bf(a0[r]);
      W2o[(size_t)(o0 + r) * 512 + 256 + t] = f2bf(a1[r]);
    }
    // bpv[o0+r] = sum_c wp[r][c]*bv[c] via per-thread 2-term partials
    float s[4];
#pragma unroll
    for (int r = 0; r < 4; ++r)
      s[r] = swp[r][t] * sbv[t] + swp[r][256 + t] * sbv[256 + t];
#pragma unroll
    for (int r = 0; r < 4; ++r)
#pragma unroll
      for (int off = 32; off > 0; off >>= 1) s[r] += __shfl_down(s[r], off);
    if ((t & 63) == 0) {
#pragma unroll
      for (int r = 0; r < 4; ++r) redp[r][t >> 6] = s[r];
    }
    __syncthreads();
    if (t == 0) {
#pragma unroll
      for (int r = 0; r < 4; ++r)
        bpv[o0 + r] = redp[r][0] + redp[r][1] + redp[r][2] + redp[r][3];
    }
    return;
  }
  if (blockIdx.x >= 512) {  // ---- qk weights fp32 -> bf16, bias, rowsum ----
    const int idx = (blockIdx.x - 512) * 256 + t;  // 0..262143
    oqk[idx] = f2bf(wq[idx]);
    oqk[262144 + idx] = f2bf(wk[idx]);
    if (idx < 1024) bqk[idx] = idx < 512 ? bq[idx] : bk[idx - 512];
    if (idx < 16384) rowsum[idx] = 0.f;
    return;
  }
  // ---- GroupNorm -> hT[b][i][c] bf16 (transposed), single pass ----
  __shared__ float red[2][4];
  const int b = blockIdx.x >> 5;
  const int g = blockIdx.x & 31;
  const int wid = t >> 6, lane = t & 63;
  const float* xp = x + ((size_t)(b * 512 + g * 16)) * 1024;

  float4 r4[16];  // 16 chans x 4 consecutive hw-elements (i = 4t..4t+3)
  float s = 0.f, s2 = 0.f;
#pragma unroll
  for (int c = 0; c < 16; ++c) {
    r4[c] = ((const float4*)(xp + (size_t)c * 1024))[t];
    s += (r4[c].x + r4[c].y) + (r4[c].z + r4[c].w);
    s2 += (r4[c].x * r4[c].x + r4[c].y * r4[c].y) +
          (r4[c].z * r4[c].z + r4[c].w * r4[c].w);
  }
#pragma unroll
  for (int off = 32; off > 0; off >>= 1) {
    s += __shfl_down(s, off);
    s2 += __shfl_down(s2, off);
  }
  if (lane == 0) { red[0][wid] = s; red[1][wid] = s2; }
  __syncthreads();
  const float S = red[0][0] + red[0][1] + red[0][2] + red[0][3];
  const float S2 = red[1][0] + red[1][1] + red[1][2] + red[1][3];
  const float mean = S * (1.f / 16384.f);
  const float var = S2 * (1.f / 16384.f) - mean * mean;
  const float rstd = rsqrtf(var + 1e-6f);

  float sc[16], bi[16];
#pragma unroll
  for (int c = 0; c < 16; ++c) {
    sc[c] = gsc[g * 16 + c] * rstd;
    bi[c] = gbi[g * 16 + c] - mean * sc[c];
  }
  unsigned short* hp = hT + (size_t)b * 1024 * 512 + g * 16;
#pragma unroll
  for (int ii = 0; ii < 4; ++ii) {  // ii indexes float4 component
    const int i = 4 * t + ii;
    unsigned int pk[8];
#pragma unroll
    for (int c = 0; c < 8; ++c) {
      float e0, e1;
      if (ii == 0) { e0 = r4[2 * c].x; e1 = r4[2 * c + 1].x; }
      else if (ii == 1) { e0 = r4[2 * c].y; e1 = r4[2 * c + 1].y; }
      else if (ii == 2) { e0 = r4[2 * c].z; e1 = r4[2 * c + 1].z; }
      else { e0 = r4[2 * c].w; e1 = r4[2 * c + 1].w; }
      float v0 = e0 * sc[2 * c] + bi[2 * c];
      float v1 = e1 * sc[2 * c + 1] + bi[2 * c + 1];
      pk[c] = (unsigned int)f2bf(v0) | ((unsigned int)f2bf(v1) << 16);
    }
    uint4* dst = (uint4*)(hp + (size_t)i * 512);
    dst[0] = make_uint4(pk[0], pk[1], pk[2], pk[3]);
    dst[1] = make_uint4(pk[4], pk[5], pk[6], pk[7]);
  }
}

// ------------------------- NT GEMM engine ----------------------------------
// D[m][n] = scale * sum_k A[m][k]*Bt[n][k].
// epi 0: plain  (+bias bmode{1:[gm],2:[gn]}, +resid, csplit offset)
// epi 2: exp + atomic rowsum (scores; bf16 out, row-major)
// epi 4: PV': v/rowsum[(m0>>9)*1024+gn] + bias[gm&511] + resid; fp32 row-major
struct GArgs {
  const unsigned short *A, *B;
  void* Out;
  const float *bias, *resid;
  float* rowsum;
  long long sBb, sOb;
  int lda, ldb, ldo, btshift, obf, csplit, K, bmode, nx, nwg, epi;
  float scale;
};

template <int BM>
__global__ __launch_bounds__(256, (BM == 256 ? 2 : 3)) void gemm_nt(
    GArgs g0, GArgs g1, int split) {
  constexpr int MF = BM / 32;      // m-frags per wave (8 / 4)
  constexpr int WMS = BM / 2;      // wave m-span (128 / 64)
  constexpr int ASLABS = BM / 32;  // A staging slabs (8 / 4)
  constexpr int BOFF = BM * 128;   // byte offset of B region in LDS
  __shared__ char lds[BM * 128 + 16384];

  const bool r1 = (int)blockIdx.x >= split;
  const GArgs g = r1 ? g1 : g0;
  const int lid = blockIdx.x - (r1 ? split : 0);

  // XCD-chunked remap within role (nwg % 8 == 0 for all our grids)
  const int cpx = g.nwg >> 3;
  const int rid = (lid & 7) * cpx + (lid >> 3);
  const int bx = rid % g.nx, by = rid / g.nx;
  const int m0 = by * BM, n0 = bx * 128;

  const int t = threadIdx.x;
  const int wid = t >> 6, lane = t & 63;
  const int srow = t >> 3;                        // 32-row slab row
  const int schunk = ((t & 7) ^ (srow & 7)) * 8;  // pre-swizzled src chunk
  const unsigned short* gA = g.A + (size_t)(m0 + srow) * g.lda + schunk;
  const unsigned short* gB =
      g.B + (g.btshift ? (size_t)(m0 >> g.btshift) * g.sBb : 0) +
      (size_t)(n0 + srow) * g.ldb + schunk;
  const int stgO = wid << 10;  // wave-uniform 1KB sub-slab

  f32x4 acc[MF][4] = {};
  const int wm = wid >> 1, wn = wid & 1;
  const int fr = lane & 15;
  const int slot0 = (((lane >> 4) ^ (fr & 7)) << 4);
  const int aoff = (wm * WMS + fr) * 128 + slot0;
  const int boff = BOFF + (wn * 64 + fr) * 128 + slot0;

  const int nt = g.K >> 6;
  for (int tt = 0; tt < nt; ++tt) {
    const size_t ko = (size_t)tt * 64;
#pragma unroll
    for (int c = 0; c < ASLABS; ++c)
      GLD16(gA + ko + (size_t)(c * 32) * g.lda, lds + c * 4096 + stgO);
#pragma unroll
    for (int c = 0; c < 4; ++c)
      GLD16(gB + ko + (size_t)(c * 32) * g.ldb, lds + BOFF + c * 4096 + stgO);
    __syncthreads();  // drains vmcnt -> tile visible to all waves
#pragma unroll
    for (int kk = 0; kk < 2; ++kk) {
      const int kx = kk ? 64 : 0;  // second k-half: chunk slot ^= 4
      bf16x8 av[MF], bv[4];
#pragma unroll
      for (int mf = 0; mf < MF; ++mf)
        av[mf] = *(const bf16x8*)(lds + ((aoff + mf * 2048) ^ kx));
#pragma unroll
      for (int nf = 0; nf < 4; ++nf)
        bv[nf] = *(const bf16x8*)(lds + ((boff + nf * 2048) ^ kx));
      __builtin_amdgcn_s_setprio(1);
#pragma unroll
      for (int mf = 0; mf < MF; ++mf)
#pragma unroll
        for (int nf = 0; nf < 4; ++nf)
          acc[mf][nf] = __builtin_amdgcn_mfma_f32_16x16x32_bf16(
              av[mf], bv[nf], acc[mf][nf], 0, 0, 0);
      __builtin_amdgcn_s_setprio(0);
    }
    __syncthreads();  // protect LDS before next stage
  }

  const int em = m0 + wm * WMS + (lane >> 4) * 4;
  const int en = n0 + wn * 64 + fr;

  float rdiv[4];
  if (g.epi == 4) {
    const int rbase = (m0 >> 9) << 10;  // batch = m0>>9, E-row base
#pragma unroll
    for (int nf = 0; nf < 4; ++nf)
      rdiv[nf] = 1.f / g.rowsum[rbase + en + nf * 16];
  }

#pragma unroll
  for (int mf = 0; mf < MF; ++mf) {
#pragma unroll
    for (int r = 0; r < 4; ++r) {
      const int gm = em + mf * 16 + r;
      if (g.epi == 2) {  // scores: exp, atomic row sum of ROUNDED values
        float rsum = 0.f;
#pragma unroll
        for (int nf = 0; nf < 4; ++nf) {
          const int gn = en + nf * 16;
          unsigned short h = f2bf(__expf(acc[mf][nf][r] * g.scale));
          rsum += bf2f(h);
          ((unsigned short*)g.Out)[(size_t)gm * g.ldo + gn] = h;
        }
        rsum += __shfl_xor(rsum, 1);
        rsum += __shfl_xor(rsum, 2);
        rsum += __shfl_xor(rsum, 4);
        rsum += __shfl_xor(rsum, 8);
        if ((lane & 15) == 0) atomicAdd(&g.rowsum[gm], rsum);
        continue;
      }
      if (g.epi == 4) {  // PV': normalize + bias + resid, fp32 row-major
        const float bb = g.bias[gm & 511];
#pragma unroll
        for (int nf = 0; nf < 4; ++nf) {
          const int gn = en + nf * 16;
          const size_t off = (size_t)gm * g.ldo + gn;
          ((float*)g.Out)[off] = acc[mf][nf][r] * rdiv[nf] + bb + g.resid[off];
        }
        continue;
      }
#pragma unroll
      for (int nf = 0; nf < 4; ++nf) {
        const int gn = en + nf * 16;
        float v = acc[mf][nf][r] * g.scale;
        if (g.bmode == 1) v += g.bias[gm];
        else if (g.bmode == 2) v += g.bias[gn];
        size_t off;
        if (g.csplit)
          off = (size_t)(gn >> 10) * g.sOb + (size_t)gm * g.ldo + (gn & 1023);
        else
          off = (size_t)gm * g.ldo + gn;
        if (g.resid) v += g.resid[off];
        if (g.obf) ((unsigned short*)g.Out)[off] = f2bf(v);
        else ((float*)g.Out)[off] = v;
      }
    }
  }
}

// ---------------------------------------------------------------------------
extern "C" void kernel_launch(void* const* d_in, const int* in_sizes, int n_in,
                              void* d_out, int out_size, void* d_ws,
                              size_t ws_size, hipStream_t stream) {
  const float* x   = (const float*)d_in[0];
  const float* gsc = (const float*)d_in[1];
  const float* gbi = (const float*)d_in[2];
  const float* wq  = (const float*)d_in[3];
  const float* bq  = (const float*)d_in[4];
  const float* wk  = (const float*)d_in[5];
  const float* bk  = (const float*)d_in[6];
  const float* wv  = (const float*)d_in[7];
  const float* bv  = (const float*)d_in[8];
  const float* wp  = (const float*)d_in[9];
  const float* bp  = (const float*)d_in[10];
  float* out = (float*)d_out;

  char* ws = (char*)d_ws;
  const size_t MB = 1024ull * 1024ull;
  unsigned short* hT  = (unsigned short*)(ws);             // 16MB [16384][512]
  unsigned short* qkT = (unsigned short*)(ws + 16 * MB);   // 32MB [16384][1024]
  unsigned short* E   = (unsigned short*)(ws + 48 * MB);   // 32MB [16384][1024]
  unsigned short* vP  = (unsigned short*)(ws + 80 * MB);   // 16MB [16][512][1024]
  unsigned short* wqk = (unsigned short*)(ws + 96 * MB);   // 1MB  [1024][512]
  unsigned short* W2  = (unsigned short*)(ws + 98 * MB);   // 0.5MB [512][512]
  float*          bqk = (float*)(ws + 99 * MB);            // 4KB
  float*          bpv = (float*)(ws + 99 * MB + 8 * 1024); // 2KB
  float*          rowsum = (float*)(ws + 99 * MB + 16 * 1024);  // 64KB

  prep_kernel<<<1664, 256, 0, stream>>>(x, gsc, gbi, hT, wq, wk, wv, wp,
                                        bq, bk, bv, wqk, W2,
                                        bqk, bpv, rowsum);

  const float rsK = 0.04419417382415922f;  // 512^-0.5

  // qk: qkT[m][n] = sum_c hT[m][c] wqk[n][c] + bqk[n]  (512 tiles, 1 round)
  GArgs qk{hT, wqk, qkT, bqk, nullptr, nullptr, 0, 0,
           512, 512, 1024, 0, 1, 0, 512, 2, 8, 512, 0, 1.f};
  // scores: E[m][j] = exp(rsK * q_m . k_{b,j}); rowsum atomic. b = m>>10.
  GArgs sc{qkT, qkT + 512, E, nullptr, nullptr, rowsum, 1048576, 0,
           1024, 1024, 1024, 10, 1, 0, 512, 0, 8, 512, 2, rsK};
  // vP[b][co][j] = sum_c W2[co][c] hT[(b,j)][c] + bpv[co]  (csplit writes)
  GArgs vp{W2, hT, vP, bpv, nullptr, nullptr, 0, 524288,
           512, 512, 1024, 0, 1, 1, 512, 1, 128, 512, 0, 1.f};
  // PV': out[(b,c)][i] = x + bp[c] + (sum_j vP[(b,c)][j] E[b][i][j])/rowsum
  GArgs pv{vP, E, out, bp, x, rowsum, 1048576, 0,
           1024, 1024, 1024, 9, 0, 0, 1024, 0, 8, 512, 4, 1.f};

  gemm_nt<256><<<512, 256, 0, stream>>>(qk, qk, 512);
  gemm_nt<256><<<512, 256, 0, stream>>>(sc, sc, 512);
  gemm_nt<128><<<512, 256, 0, stream>>>(vp, vp, 512);
  gemm_nt<128><<<512, 256, 0, stream>>>(pv, pv, 512);
}

// Round 15
// 177.521 us; speedup vs baseline: 1.1242x; 1.0296x over previous
//
#include <hip/hip_runtime.h>
#include <cstdint>
#include <cstddef>

// ---------------------------------------------------------------------------
// AttnBlock, 5 dispatches, every GEMM grid = exactly one resident round:
//   prep:   W2=wp.wv + bpv (blocks 0-127, LDS-staged wp);
//           qk weights bf16 + bqk + rowsum=0 (128-1151);
//           GN 2-pass vectorized -> hT[16384][512] (1152-1663)
//   qk:     qkT[16384][1024] = hT.wqk^T + bqk        (512 BM256 = 1 round)
//   scores: E[b][i][j] = exp(rsK*q.k); rowsum atomic (512 BM256 = 1 round)
//   vP:     vP[b][co][j] = sum_c W2[co][c] hT[(b,j)][c] + bpv[co] (512 BM128)
//   PV':    out[(b,c)][i] = x + bp[c] + (sum_j vP.E)/rowsum       (512 BM128)
// Engine: BM x 128 tiles, 4 waves, BK=64, chunk-swizzled LDS, XCD remap.
// launch_bounds: BM256 (256,2) / BM128 (256,3) -- (256,3) on BM256 SPILLS
// (R10: VGPR 84, 344MB scratch). Grid rule (R12): BM256 grids <= 512 blocks.
// W2 rule (R13): wave-uniform global reads in K-loop serialize as s_loads --
// stage wp/bv in LDS. GN rule (R14): r4[16] live set (64 VGPR) makes the
// compiler re-load x SCALAR; explicit 2-pass float4 re-read instead.
// ---------------------------------------------------------------------------

typedef __bf16 bf16x8 __attribute__((ext_vector_type(8)));
typedef float f32x4 __attribute__((ext_vector_type(4)));

typedef __attribute__((address_space(1))) const void gl_void;
typedef __attribute__((address_space(3))) void lds_void;

#define GLD16(g, l)                                                     \
  __builtin_amdgcn_global_load_lds((gl_void*)(uintptr_t)(g),            \
                                   (lds_void*)(uintptr_t)(l), 16, 0, 0)

__device__ __forceinline__ unsigned short f2bf(float f) {
  unsigned int u = __builtin_bit_cast(unsigned int, f);
  u += 0x7fffu + ((u >> 16) & 1u);  // round-to-nearest-even
  return (unsigned short)(u >> 16);
}
__device__ __forceinline__ float bf2f(unsigned int h) {
  return __builtin_bit_cast(float, h << 16);
}

// ---- prep: W2 (0-127) + qk weights (128-1151) + GN 2-pass (1152-1663) -----
__global__ __launch_bounds__(256) void prep_kernel(
    const float* __restrict__ x, const float* __restrict__ gsc,
    const float* __restrict__ gbi, unsigned short* __restrict__ hT,
    const float* __restrict__ wq, const float* __restrict__ wk,
    const float* __restrict__ wv, const float* __restrict__ wp,
    const float* __restrict__ bq, const float* __restrict__ bk,
    const float* __restrict__ bv, unsigned short* __restrict__ oqk,
    unsigned short* __restrict__ W2o, float* __restrict__ bqk,
    float* __restrict__ bpv, float* __restrict__ rowsum) {
  const int t = threadIdx.x;
  if (blockIdx.x < 128) {  // ---- W2 = wp.wv (fp32), bpv = wp.bv ----
    __shared__ float swp[4][512];  // wp rows in LDS (broadcast reads, no s_load)
    __shared__ float sbv[512];
    __shared__ float redp[4][4];
    const int o0 = blockIdx.x * 4;  // 4 output rows per block
#pragma unroll
    for (int r = 0; r < 4; ++r) {
      swp[r][t] = wp[(size_t)(o0 + r) * 512 + t];
      swp[r][256 + t] = wp[(size_t)(o0 + r) * 512 + 256 + t];
    }
    sbv[t] = bv[t];
    sbv[256 + t] = bv[256 + t];
    __syncthreads();
    float a0[4] = {}, a1[4] = {};
    for (int c = 0; c < 512; ++c) {
      const float v0 = wv[(size_t)c * 512 + t];        // coalesced, L2
      const float v1 = wv[(size_t)c * 512 + 256 + t];  // coalesced, L2
#pragma unroll
      for (int r = 0; r < 4; ++r) {  // swp[r][c]: LDS broadcast (cheap)
        a0[r] = fmaf(swp[r][c], v0, a0[r]);
        a1[r] = fmaf(swp[r][c], v1, a1[r]);
      }
    }
#pragma unroll
    for (int r = 0; r < 4; ++r) {
      W2o[(size_t)(o0 + r) * 512 + t] = f2bf(a0[r]);
      W2o[(size_t)(o0 + r) * 512 + 256 + t] = f2bf(a1[r]);
    }
    float s[4];
#pragma unroll
    for (int r = 0; r < 4; ++r)
      s[r] = swp[r][t] * sbv[t] + swp[r][256 + t] * sbv[256 + t];
#pragma unroll
    for (int r = 0; r < 4; ++r)
#pragma unroll
      for (int off = 32; off > 0; off >>= 1) s[r] += __shfl_down(s[r], off);
    if ((t & 63) == 0) {
#pragma unroll
      for (int r = 0; r < 4; ++r) redp[r][t >> 6] = s[r];
    }
    __syncthreads();
    if (t == 0) {
#pragma unroll
      for (int r = 0; r < 4; ++r)
        bpv[o0 + r] = redp[r][0] + redp[r][1] + redp[r][2] + redp[r][3];
    }
    return;
  }
  if (blockIdx.x < 1152) {  // ---- qk weights fp32 -> bf16, bias, rowsum ----
    const int idx = (blockIdx.x - 128) * 256 + t;  // 0..262143
    oqk[idx] = f2bf(wq[idx]);
    oqk[262144 + idx] = f2bf(wk[idx]);
    if (idx < 1024) bqk[idx] = idx < 512 ? bq[idx] : bk[idx - 512];
    if (idx < 16384) rowsum[idx] = 0.f;
    return;
  }
  // ---- GroupNorm -> hT[b][i][c] bf16, explicit 2-pass, float4 both ----
  __shared__ float red[2][4];
  const int gb = blockIdx.x - 1152;
  const int b = gb >> 5;
  const int g = gb & 31;
  const int wid = t >> 6, lane = t & 63;
  const float* xp = x + ((size_t)(b * 512 + g * 16)) * 1024;

  // pass 1: stream + accumulate (no live array)
  float s = 0.f, s2 = 0.f;
#pragma unroll
  for (int c = 0; c < 16; ++c) {
    const float4 v = ((const float4*)(xp + (size_t)c * 1024))[t];
    s += (v.x + v.y) + (v.z + v.w);
    s2 += (v.x * v.x + v.y * v.y) + (v.z * v.z + v.w * v.w);
  }
#pragma unroll
  for (int off = 32; off > 0; off >>= 1) {
    s += __shfl_down(s, off);
    s2 += __shfl_down(s2, off);
  }
  if (lane == 0) { red[0][wid] = s; red[1][wid] = s2; }
  __syncthreads();
  const float S = red[0][0] + red[0][1] + red[0][2] + red[0][3];
  const float S2 = red[1][0] + red[1][1] + red[1][2] + red[1][3];
  const float mean = S * (1.f / 16384.f);
  const float var = S2 * (1.f / 16384.f) - mean * mean;
  const float rstd = rsqrtf(var + 1e-6f);

  float sc[16], bi[16];
#pragma unroll
  for (int c = 0; c < 16; ++c) {
    sc[c] = gsc[g * 16 + c] * rstd;
    bi[c] = gbi[g * 16 + c] - mean * sc[c];
  }
  // pass 2: re-read (L2-hot) in two 8-channel halves, float4-vectorized
  unsigned short* hp = hT + (size_t)b * 1024 * 512 + g * 16;
#pragma unroll
  for (int half = 0; half < 2; ++half) {
    float4 r4[8];
#pragma unroll
    for (int c = 0; c < 8; ++c)
      r4[c] = ((const float4*)(xp + (size_t)(half * 8 + c) * 1024))[t];
#pragma unroll
    for (int ii = 0; ii < 4; ++ii) {  // float4 component = row 4t+ii
      const int i = 4 * t + ii;
      unsigned int pk[4];
#pragma unroll
      for (int p = 0; p < 4; ++p) {
        const int c0 = half * 8 + 2 * p;
        float e0, e1;
        if (ii == 0) { e0 = r4[2 * p].x; e1 = r4[2 * p + 1].x; }
        else if (ii == 1) { e0 = r4[2 * p].y; e1 = r4[2 * p + 1].y; }
        else if (ii == 2) { e0 = r4[2 * p].z; e1 = r4[2 * p + 1].z; }
        else { e0 = r4[2 * p].w; e1 = r4[2 * p + 1].w; }
        const float v0 = e0 * sc[c0] + bi[c0];
        const float v1 = e1 * sc[c0 + 1] + bi[c0 + 1];
        pk[p] = (unsigned int)f2bf(v0) | ((unsigned int)f2bf(v1) << 16);
      }
      *(uint4*)(hp + (size_t)i * 512 + half * 8) =
          make_uint4(pk[0], pk[1], pk[2], pk[3]);
    }
  }
}

// ------------------------- NT GEMM engine ----------------------------------
// D[m][n] = scale * sum_k A[m][k]*Bt[n][k].
// epi 0: plain  (+bias bmode{1:[gm],2:[gn]}, +resid, csplit offset)
// epi 2: exp + atomic rowsum (scores; bf16 out, row-major)
// epi 4: PV': v/rowsum[(m0>>9)*1024+gn] + bias[gm&511] + resid; fp32 row-major
struct GArgs {
  const unsigned short *A, *B;
  void* Out;
  const float *bias, *resid;
  float* rowsum;
  long long sBb, sOb;
  int lda, ldb, ldo, btshift, obf, csplit, K, bmode, nx, nwg, epi;
  float scale;
};

template <int BM>
__global__ __launch_bounds__(256, (BM == 256 ? 2 : 3)) void gemm_nt(
    GArgs g0, GArgs g1, int split) {
  constexpr int MF = BM / 32;      // m-frags per wave (8 / 4)
  constexpr int WMS = BM / 2;      // wave m-span (128 / 64)
  constexpr int ASLABS = BM / 32;  // A staging slabs (8 / 4)
  constexpr int BOFF = BM * 128;   // byte offset of B region in LDS
  __shared__ char lds[BM * 128 + 16384];

  const bool r1 = (int)blockIdx.x >= split;
  const GArgs g = r1 ? g1 : g0;
  const int lid = blockIdx.x - (r1 ? split : 0);

  // XCD-chunked remap within role (nwg % 8 == 0 for all our grids)
  const int cpx = g.nwg >> 3;
  const int rid = (lid & 7) * cpx + (lid >> 3);
  const int bx = rid % g.nx, by = rid / g.nx;
  const int m0 = by * BM, n0 = bx * 128;

  const int t = threadIdx.x;
  const int wid = t >> 6, lane = t & 63;
  const int srow = t >> 3;                        // 32-row slab row
  const int schunk = ((t & 7) ^ (srow & 7)) * 8;  // pre-swizzled src chunk
  const unsigned short* gA = g.A + (size_t)(m0 + srow) * g.lda + schunk;
  const unsigned short* gB =
      g.B + (g.btshift ? (size_t)(m0 >> g.btshift) * g.sBb : 0) +
      (size_t)(n0 + srow) * g.ldb + schunk;
  const int stgO = wid << 10;  // wave-uniform 1KB sub-slab

  f32x4 acc[MF][4] = {};
  const int wm = wid >> 1, wn = wid & 1;
  const int fr = lane & 15;
  const int slot0 = (((lane >> 4) ^ (fr & 7)) << 4);
  const int aoff = (wm * WMS + fr) * 128 + slot0;
  const int boff = BOFF + (wn * 64 + fr) * 128 + slot0;

  const int nt = g.K >> 6;
  for (int tt = 0; tt < nt; ++tt) {
    const size_t ko = (size_t)tt * 64;
#pragma unroll
    for (int c = 0; c < ASLABS; ++c)
      GLD16(gA + ko + (size_t)(c * 32) * g.lda, lds + c * 4096 + stgO);
#pragma unroll
    for (int c = 0; c < 4; ++c)
      GLD16(gB + ko + (size_t)(c * 32) * g.ldb, lds + BOFF + c * 4096 + stgO);
    __syncthreads();  // drains vmcnt -> tile visible to all waves
#pragma unroll
    for (int kk = 0; kk < 2; ++kk) {
      const int kx = kk ? 64 : 0;  // second k-half: chunk slot ^= 4
      bf16x8 av[MF], bv[4];
#pragma unroll
      for (int mf = 0; mf < MF; ++mf)
        av[mf] = *(const bf16x8*)(lds + ((aoff + mf * 2048) ^ kx));
#pragma unroll
      for (int nf = 0; nf < 4; ++nf)
        bv[nf] = *(const bf16x8*)(lds + ((boff + nf * 2048) ^ kx));
      __builtin_amdgcn_s_setprio(1);
#pragma unroll
      for (int mf = 0; mf < MF; ++mf)
#pragma unroll
        for (int nf = 0; nf < 4; ++nf)
          acc[mf][nf] = __builtin_amdgcn_mfma_f32_16x16x32_bf16(
              av[mf], bv[nf], acc[mf][nf], 0, 0, 0);
      __builtin_amdgcn_s_setprio(0);
    }
    __syncthreads();  // protect LDS before next stage
  }

  const int em = m0 + wm * WMS + (lane >> 4) * 4;
  const int en = n0 + wn * 64 + fr;

  float rdiv[4];
  if (g.epi == 4) {
    const int rbase = (m0 >> 9) << 10;  // batch = m0>>9, E-row base
#pragma unroll
    for (int nf = 0; nf < 4; ++nf)
      rdiv[nf] = 1.f / g.rowsum[rbase + en + nf * 16];
  }

#pragma unroll
  for (int mf = 0; mf < MF; ++mf) {
#pragma unroll
    for (int r = 0; r < 4; ++r) {
      const int gm = em + mf * 16 + r;
      if (g.epi == 2) {  // scores: exp, atomic row sum of ROUNDED values
        float rsum = 0.f;
#pragma unroll
        for (int nf = 0; nf < 4; ++nf) {
          const int gn = en + nf * 16;
          unsigned short h = f2bf(__expf(acc[mf][nf][r] * g.scale));
          rsum += bf2f(h);
          ((unsigned short*)g.Out)[(size_t)gm * g.ldo + gn] = h;
        }
        rsum += __shfl_xor(rsum, 1);
        rsum += __shfl_xor(rsum, 2);
        rsum += __shfl_xor(rsum, 4);
        rsum += __shfl_xor(rsum, 8);
        if ((lane & 15) == 0) atomicAdd(&g.rowsum[gm], rsum);
        continue;
      }
      if (g.epi == 4) {  // PV': normalize + bias + resid, fp32 row-major
        const float bb = g.bias[gm & 511];
#pragma unroll
        for (int nf = 0; nf < 4; ++nf) {
          const int gn = en + nf * 16;
          const size_t off = (size_t)gm * g.ldo + gn;
          ((float*)g.Out)[off] = acc[mf][nf][r] * rdiv[nf] + bb + g.resid[off];
        }
        continue;
      }
#pragma unroll
      for (int nf = 0; nf < 4; ++nf) {
        const int gn = en + nf * 16;
        float v = acc[mf][nf][r] * g.scale;
        if (g.bmode == 1) v += g.bias[gm];
        else if (g.bmode == 2) v += g.bias[gn];
        size_t off;
        if (g.csplit)
          off = (size_t)(gn >> 10) * g.sOb + (size_t)gm * g.ldo + (gn & 1023);
        else
          off = (size_t)gm * g.ldo + gn;
        if (g.resid) v += g.resid[off];
        if (g.obf) ((unsigned short*)g.Out)[off] = f2bf(v);
        else ((float*)g.Out)[off] = v;
      }
    }
  }
}

// ---------------------------------------------------------------------------
extern "C" void kernel_launch(void* const* d_in, const int* in_sizes, int n_in,
                              void* d_out, int out_size, void* d_ws,
                              size_t ws_size, hipStream_t stream) {
  const float* x   = (const float*)d_in[0];
  const float* gsc = (const float*)d_in[1];
  const float* gbi = (const float*)d_in[2];
  const float* wq  = (const float*)d_in[3];
  const float* bq  = (const float*)d_in[4];
  const float* wk  = (const float*)d_in[5];
  const float* bk  = (const float*)d_in[6];
  const float* wv  = (const float*)d_in[7];
  const float* bv  = (const float*)d_in[8];
  const float* wp  = (const float*)d_in[9];
  const float* bp  = (const float*)d_in[10];
  float* out = (float*)d_out;

  char* ws = (char*)d_ws;
  const size_t MB = 1024ull * 1024ull;
  unsigned short* hT  = (unsigned short*)(ws);             // 16MB [16384][512]
  unsigned short* qkT = (unsigned short*)(ws + 16 * MB);   // 32MB [16384][1024]
  unsigned short* E   = (unsigned short*)(ws + 48 * MB);   // 32MB [16384][1024]
  unsigned short* vP  = (unsigned short*)(ws + 80 * MB);   // 16MB [16][512][1024]
  unsigned short* wqk = (unsigned short*)(ws + 96 * MB);   // 1MB  [1024][512]
  unsigned short* W2  = (unsigned short*)(ws + 98 * MB);   // 0.5MB [512][512]
  float*          bqk = (float*)(ws + 99 * MB);            // 4KB
  float*          bpv = (float*)(ws + 99 * MB + 8 * 1024); // 2KB
  float*          rowsum = (float*)(ws + 99 * MB + 16 * 1024);  // 64KB

  prep_kernel<<<1664, 256, 0, stream>>>(x, gsc, gbi, hT, wq, wk, wv, wp,
                                        bq, bk, bv, wqk, W2,
                                        bqk, bpv, rowsum);

  const float rsK = 0.04419417382415922f;  // 512^-0.5

  // qk: qkT[m][n] = sum_c hT[m][c] wqk[n][c] + bqk[n]  (512 tiles, 1 round)
  GArgs qk{hT, wqk, qkT, bqk, nullptr, nullptr, 0, 0,
           512, 512, 1024, 0, 1, 0, 512, 2, 8, 512, 0, 1.f};
  // scores: E[m][j] = exp(rsK * q_m . k_{b,j}); rowsum atomic. b = m>>10.
  GArgs sc{qkT, qkT + 512, E, nullptr, nullptr, rowsum, 1048576, 0,
           1024, 1024, 1024, 10, 1, 0, 512, 0, 8, 512, 2, rsK};
  // vP[b][co][j] = sum_c W2[co][c] hT[(b,j)][c] + bpv[co]  (csplit writes)
  GArgs vp{W2, hT, vP, bpv, nullptr, nullptr, 0, 524288,
           512, 512, 1024, 0, 1, 1, 512, 1, 128, 512, 0, 1.f};
  // PV': out[(b,c)][i] = x + bp[c] + (sum_j vP[(b,c)][j] E[b][i][j])/rowsum
  GArgs pv{vP, E, out, bp, x, rowsum, 1048576, 0,
           1024, 1024, 1024, 9, 0, 0, 1024, 0, 8, 512, 4, 1.f};

  gemm_nt<256><<<512, 256, 0, stream>>>(qk, qk, 512);
  gemm_nt<256><<<512, 256, 0, stream>>>(sc, sc, 512);
  gemm_nt<128><<<512, 256, 0, stream>>>(vp, vp, 512);
  gemm_nt<128><<<512, 256, 0, stream>>>(pv, pv, 512);
}